// Round 3
// baseline (793.120 us; speedup 1.0000x reference)
//
#include <hip/hip_runtime.h>

#define B_  4
#define N_  4096
#define C_  256
#define D_  128
#define M_  4095
#define BN_ (B_ * N_)

// ---------------- projections: theta/phi/g = x @ {Wt,Wp,Wg} ----------------
// grid: (BN_/64, 3), block: 256.  LDS = 51,200 B.
__global__ __launch_bounds__(256) void proj_kernel(
    const float* __restrict__ x,
    const float* __restrict__ Wt, const float* __restrict__ Wp,
    const float* __restrict__ Wg, float* __restrict__ ws)
{
    const int tid = threadIdx.x;
    const int rb = blockIdx.x;
    const int which = blockIdx.y;
    const float* __restrict__ W = (which == 0) ? Wt : (which == 1) ? Wp : Wg;
    float* __restrict__ outp = ws + (size_t)which * BN_ * D_;

    __shared__ float Xs[64][68];
    __shared__ float Wsh[64][132];

    const int tr = tid >> 4;   // 0..15
    const int tk = tid & 15;   // 0..15
    const int r0 = rb * 64;

    float acc[4][8];
#pragma unroll
    for (int i = 0; i < 4; ++i)
#pragma unroll
        for (int j = 0; j < 8; ++j) acc[i][j] = 0.f;

    for (int kc = 0; kc < 4; ++kc) {   // K = 256 in chunks of 64
        __syncthreads();
#pragma unroll
        for (int i = 0; i < 4; ++i) {           // 64x64 tile = 1024 float4
            int t = i * 256 + tid;
            int r = t >> 4, c4 = (t & 15) * 4;
            *(float4*)&Xs[r][c4] =
                *(const float4*)&x[(size_t)(r0 + r) * C_ + kc * 64 + c4];
        }
#pragma unroll
        for (int i = 0; i < 8; ++i) {           // 64x128 tile = 2048 float4
            int t = i * 256 + tid;
            int r = t >> 5, c4 = (t & 31) * 4;
            *(float4*)&Wsh[r][c4] =
                *(const float4*)&W[(size_t)(kc * 64 + r) * D_ + c4];
        }
        __syncthreads();

        for (int k4 = 0; k4 < 64; k4 += 4) {
            float4 a[4];
#pragma unroll
            for (int i = 0; i < 4; ++i)
                a[i] = *(const float4*)&Xs[tr + 16 * i][k4];
#pragma unroll
            for (int kk = 0; kk < 4; ++kk) {
                const float4 b0 = *(const float4*)&Wsh[k4 + kk][tk * 8];
                const float4 b1 = *(const float4*)&Wsh[k4 + kk][tk * 8 + 4];
#pragma unroll
                for (int i = 0; i < 4; ++i) {
                    const float av = (kk == 0) ? a[i].x : (kk == 1) ? a[i].y
                                    : (kk == 2) ? a[i].z : a[i].w;
                    acc[i][0] += av * b0.x; acc[i][1] += av * b0.y;
                    acc[i][2] += av * b0.z; acc[i][3] += av * b0.w;
                    acc[i][4] += av * b1.x; acc[i][5] += av * b1.y;
                    acc[i][6] += av * b1.z; acc[i][7] += av * b1.w;
                }
            }
        }
    }
#pragma unroll
    for (int i = 0; i < 4; ++i) {
        float* orow = outp + (size_t)(r0 + tr + 16 * i) * D_ + tk * 8;
        float4 o0, o1;
        o0.x = acc[i][0]; o0.y = acc[i][1]; o0.z = acc[i][2]; o0.w = acc[i][3];
        o1.x = acc[i][4]; o1.y = acc[i][5]; o1.z = acc[i][6]; o1.w = acc[i][7];
        *(float4*)&orow[0] = o0;
        *(float4*)&orow[4] = o1;
    }
}

// ---------------- pre-pool: maxpool(2,1) on phi and g ----------------
// grid: BN_*32/256 = 2048, block 256. One float4 per thread.
__global__ __launch_bounds__(256) void pool_kernel(
    const float* __restrict__ phi, const float* __restrict__ g,
    float* __restrict__ pphi, float* __restrict__ pg)
{
    const int idx4 = blockIdx.x * 256 + threadIdx.x;   // 0 .. BN_*32-1
    const int row = idx4 >> 5;            // global row 0..16383
    const int m = row & (N_ - 1);         // row within batch
    const size_t base = (size_t)row * D_ + (idx4 & 31) * 4;

    float4 a = *(const float4*)&phi[base];
    float4 v = *(const float4*)&g[base];
    if (m < N_ - 1) {
        const float4 a2 = *(const float4*)&phi[base + D_];
        const float4 v2 = *(const float4*)&g[base + D_];
        a.x = fmaxf(a.x, a2.x); a.y = fmaxf(a.y, a2.y);
        a.z = fmaxf(a.z, a2.z); a.w = fmaxf(a.w, a2.w);
        v.x = fmaxf(v.x, v2.x); v.y = fmaxf(v.y, v2.y);
        v.z = fmaxf(v.z, v2.z); v.w = fmaxf(v.w, v2.w);
    }
    *(float4*)&pphi[base] = a;
    *(float4*)&pg[base]   = v;
}

// ---------------- flash attention (pooled inputs) ----------------
// grid: (N_/32 = 128, B_), block 256. LDS = 59,392 B (2 blocks/CU).
__global__ __launch_bounds__(256) void attn_kernel(
    const float* __restrict__ theta, const float* __restrict__ pphi,
    const float* __restrict__ pg, float* __restrict__ ws_y)
{
    const int tid = threadIdx.x;
    const int q0 = blockIdx.x * 32;
    const int b  = blockIdx.y;
    const float* __restrict__ th = theta + (size_t)b * N_ * D_;
    const float* __restrict__ pp = pphi  + (size_t)b * N_ * D_;
    const float* __restrict__ pv = pg    + (size_t)b * N_ * D_;

    __shared__ float Qs[32][132];    // 16,896 B
    __shared__ float KGs[64][132];   // 33,792 B (K tile, then G tile)
    __shared__ float Ps[32][68];     //  8,704 B

    const int tr = tid >> 4;   // 0..15 : query rows tr, tr+16
    const int tk = tid & 15;   // 0..15 : keys tk+16j / y-cols tk*8+u

    // load Q tile (32 x 128) = 1024 float4
#pragma unroll
    for (int i = 0; i < 4; ++i) {
        int t = i * 256 + tid;
        int r = t >> 5, c4 = (t & 31) * 4;
        *(float4*)&Qs[r][c4] = *(const float4*)&th[(size_t)(q0 + r) * D_ + c4];
    }

    float m_i[2] = {-1e30f, -1e30f};
    float l_i[2] = {0.f, 0.f};
    float yacc[2][8];
#pragma unroll
    for (int i = 0; i < 2; ++i)
#pragma unroll
        for (int u = 0; u < 8; ++u) yacc[i][u] = 0.f;

    for (int kt = 0; kt < 64; ++kt) {
        const int k0 = kt * 64;
        __syncthreads();   // prev PV done (KGs/Ps reusable); orders Qs load too
        // load pooled-K tile (64 x 128) = 2048 float4
#pragma unroll
        for (int i = 0; i < 8; ++i) {
            int t = i * 256 + tid;
            int r = t >> 5, c4 = (t & 31) * 4;
            *(float4*)&KGs[r][c4] = *(const float4*)&pp[(size_t)(k0 + r) * D_ + c4];
        }
        __syncthreads();

        // QK^T : sc[i][j] = Q[tr+16i] . K[tk+16j]
        float sc[2][4];
#pragma unroll
        for (int i = 0; i < 2; ++i)
#pragma unroll
            for (int j = 0; j < 4; ++j) sc[i][j] = 0.f;

        for (int d = 0; d < 128; d += 4) {
            float4 qv[2], kv[4];
            qv[0] = *(const float4*)&Qs[tr][d];
            qv[1] = *(const float4*)&Qs[tr + 16][d];
#pragma unroll
            for (int j = 0; j < 4; ++j) kv[j] = *(const float4*)&KGs[tk + 16 * j][d];
#pragma unroll
            for (int i = 0; i < 2; ++i)
#pragma unroll
                for (int j = 0; j < 4; ++j)
                    sc[i][j] += qv[i].x * kv[j].x + qv[i].y * kv[j].y
                              + qv[i].z * kv[j].z + qv[i].w * kv[j].w;
        }
        // mask padded key (index M_ == 4095)
#pragma unroll
        for (int j = 0; j < 4; ++j) {
            if (k0 + tk + 16 * j >= M_) { sc[0][j] = -1e30f; sc[1][j] = -1e30f; }
        }
        // online softmax per row (16-lane tk group reduction)
        float alpha[2];
#pragma unroll
        for (int i = 0; i < 2; ++i) {
            float mt = fmaxf(fmaxf(sc[i][0], sc[i][1]), fmaxf(sc[i][2], sc[i][3]));
#pragma unroll
            for (int off = 1; off < 16; off <<= 1)
                mt = fmaxf(mt, __shfl_xor(mt, off, 16));
            const float mnew = fmaxf(m_i[i], mt);
            alpha[i] = __expf(m_i[i] - mnew);
            float rs = 0.f;
#pragma unroll
            for (int j = 0; j < 4; ++j) {
                float p = __expf(sc[i][j] - mnew);
                sc[i][j] = p;
                rs += p;
                Ps[tr + 16 * i][tk + 16 * j] = p;
            }
#pragma unroll
            for (int off = 1; off < 16; off <<= 1)
                rs += __shfl_xor(rs, off, 16);
            l_i[i] = l_i[i] * alpha[i] + rs;
            m_i[i] = mnew;
        }
        __syncthreads();   // QK reads of KGs done; Ps visible
        // load pooled-G tile into the same buffer
#pragma unroll
        for (int i = 0; i < 8; ++i) {
            int t = i * 256 + tid;
            int r = t >> 5, c4 = (t & 31) * 4;
            *(float4*)&KGs[r][c4] = *(const float4*)&pv[(size_t)(k0 + r) * D_ + c4];
        }
        __syncthreads();

        // PV : yacc[i][u] = yacc[i][u]*alpha[i] + sum_k P[row_i][k]*G[k][tk*8+u]
#pragma unroll
        for (int i = 0; i < 2; ++i)
#pragma unroll
            for (int u = 0; u < 8; ++u) yacc[i][u] *= alpha[i];

        for (int k4 = 0; k4 < 64; k4 += 4) {
            float4 p0 = *(const float4*)&Ps[tr][k4];
            float4 p1 = *(const float4*)&Ps[tr + 16][k4];
#pragma unroll
            for (int kk = 0; kk < 4; ++kk) {
                const float4 g0 = *(const float4*)&KGs[k4 + kk][tk * 8];
                const float4 g1 = *(const float4*)&KGs[k4 + kk][tk * 8 + 4];
                const float pa = (kk == 0) ? p0.x : (kk == 1) ? p0.y : (kk == 2) ? p0.z : p0.w;
                const float pb = (kk == 0) ? p1.x : (kk == 1) ? p1.y : (kk == 2) ? p1.z : p1.w;
                yacc[0][0] += pa * g0.x; yacc[0][1] += pa * g0.y;
                yacc[0][2] += pa * g0.z; yacc[0][3] += pa * g0.w;
                yacc[0][4] += pa * g1.x; yacc[0][5] += pa * g1.y;
                yacc[0][6] += pa * g1.z; yacc[0][7] += pa * g1.w;
                yacc[1][0] += pb * g0.x; yacc[1][1] += pb * g0.y;
                yacc[1][2] += pb * g0.z; yacc[1][3] += pb * g0.w;
                yacc[1][4] += pb * g1.x; yacc[1][5] += pb * g1.y;
                yacc[1][6] += pb * g1.z; yacc[1][7] += pb * g1.w;
            }
        }
    }

    // epilogue: y = yacc / l
    float* __restrict__ yb = ws_y + (size_t)b * N_ * D_;
#pragma unroll
    for (int i = 0; i < 2; ++i) {
        const float invl = 1.0f / l_i[i];
        float* row = yb + (size_t)(q0 + tr + 16 * i) * D_ + tk * 8;
        float4 o0, o1;
        o0.x = yacc[i][0] * invl; o0.y = yacc[i][1] * invl;
        o0.z = yacc[i][2] * invl; o0.w = yacc[i][3] * invl;
        o1.x = yacc[i][4] * invl; o1.y = yacc[i][5] * invl;
        o1.z = yacc[i][6] * invl; o1.w = yacc[i][7] * invl;
        *(float4*)&row[0] = o0;
        *(float4*)&row[4] = o1;
    }
}

// ---------------- final: z = x + y @ Wf ----------------
// grid: (BN_/64, C_/64), block 256. LDS = 34,816 B.
__global__ __launch_bounds__(256) void final_kernel(
    const float* __restrict__ ws_y, const float* __restrict__ x,
    const float* __restrict__ Wf, float* __restrict__ out)
{
    const int tid = threadIdx.x;
    const int rb = blockIdx.x;
    const int cb = blockIdx.y;
    const int r0 = rb * 64, c0 = cb * 64;

    __shared__ float Ys[64][68];
    __shared__ float Wfs[64][68];

    const int tr = tid >> 4;
    const int tk = tid & 15;

    float acc[4][4];
#pragma unroll
    for (int i = 0; i < 4; ++i)
#pragma unroll
        for (int j = 0; j < 4; ++j) acc[i][j] = 0.f;

    for (int kc = 0; kc < 2; ++kc) {   // K = 128 in chunks of 64
        __syncthreads();
#pragma unroll
        for (int i = 0; i < 4; ++i) {   // 64x64 each = 1024 float4
            int t = i * 256 + tid;
            int r = t >> 4, c4 = (t & 15) * 4;
            *(float4*)&Ys[r][c4] =
                *(const float4*)&ws_y[(size_t)(r0 + r) * D_ + kc * 64 + c4];
            *(float4*)&Wfs[r][c4] =
                *(const float4*)&Wf[(size_t)(kc * 64 + r) * C_ + c0 + c4];
        }
        __syncthreads();

        for (int k4 = 0; k4 < 64; k4 += 4) {
            float4 a[4];
#pragma unroll
            for (int i = 0; i < 4; ++i)
                a[i] = *(const float4*)&Ys[tr + 16 * i][k4];
#pragma unroll
            for (int kk = 0; kk < 4; ++kk) {
                const float4 bv = *(const float4*)&Wfs[k4 + kk][tk * 4];
#pragma unroll
                for (int i = 0; i < 4; ++i) {
                    const float av = (kk == 0) ? a[i].x : (kk == 1) ? a[i].y
                                    : (kk == 2) ? a[i].z : a[i].w;
                    acc[i][0] += av * bv.x; acc[i][1] += av * bv.y;
                    acc[i][2] += av * bv.z; acc[i][3] += av * bv.w;
                }
            }
        }
    }
    // residual + store fp32
#pragma unroll
    for (int i = 0; i < 4; ++i) {
        const int r = r0 + tr + 16 * i;
        const int c = c0 + tk * 4;
        const float4 xr = *(const float4*)&x[(size_t)r * C_ + c];
        float4 o;
        o.x = acc[i][0] + xr.x; o.y = acc[i][1] + xr.y;
        o.z = acc[i][2] + xr.z; o.w = acc[i][3] + xr.w;
        *(float4*)&out[(size_t)r * C_ + c] = o;
    }
}

extern "C" void kernel_launch(void* const* d_in, const int* in_sizes, int n_in,
                              void* d_out, int out_size, void* d_ws, size_t ws_size,
                              hipStream_t stream)
{
    const float* x  = (const float*)d_in[0];
    const float* Wt = (const float*)d_in[1];
    const float* Wp = (const float*)d_in[2];
    const float* Wg = (const float*)d_in[3];
    const float* Wf = (const float*)d_in[4];
    float* out = (float*)d_out;

    // ws (fp32 words): theta | phi_raw | g_raw(->y) | pooled_phi | pooled_g
    // = 5 * 8 MB = 40 MB
    const size_t SEG = (size_t)BN_ * D_;   // 2,097,152 words
    float* ws    = (float*)d_ws;
    float* theta = ws;
    float* phi_r = ws + 1 * SEG;
    float* g_r   = ws + 2 * SEG;
    float* pphi  = ws + 3 * SEG;
    float* pg    = ws + 4 * SEG;
    float* y     = g_r;   // attn reads only theta/pphi/pg -> safe to overwrite g_r

    proj_kernel<<<dim3(BN_ / 64, 3), 256, 0, stream>>>(x, Wt, Wp, Wg, ws);
    pool_kernel<<<dim3(BN_ * 32 / 256), 256, 0, stream>>>(phi_r, g_r, pphi, pg);
    attn_kernel<<<dim3(N_ / 32, B_), 256, 0, stream>>>(theta, pphi, pg, y);
    final_kernel<<<dim3(BN_ / 64, C_ / 64), 256, 0, stream>>>(y, x, Wf, out);
}

// Round 4
// 234.474 us; speedup vs baseline: 3.3825x; 3.3825x over previous
//
#include <hip/hip_runtime.h>

#define B_  4
#define N_  4096
#define C_  256
#define D_  128
#define M_  4095
#define BN_ (B_ * N_)
#define KSPLIT 4
#define KEYS_PER_SPLIT (N_ / KSPLIT)   // 1024
#define KTILES (KEYS_PER_SPLIT / 64)   // 16

typedef _Float16 half_t;
typedef __attribute__((ext_vector_type(8))) _Float16 half8;
typedef __attribute__((ext_vector_type(4))) _Float16 half4;
typedef __attribute__((ext_vector_type(4))) float f32x4;

#define MFMA16x16x32(A, B, C) __builtin_amdgcn_mfma_f32_16x16x32_f16(A, B, C, 0, 0, 0)

// ---------------- projections: theta/phi/g = x @ {Wt,Wp,Wg} (fp32 vector) ----
// grid: (BN_/64, 3), block 256. LDS = 51,200 B. (verified round 3)
__global__ __launch_bounds__(256) void proj_kernel(
    const float* __restrict__ x,
    const float* __restrict__ Wt, const float* __restrict__ Wp,
    const float* __restrict__ Wg, float* __restrict__ ws)
{
    const int tid = threadIdx.x;
    const int rb = blockIdx.x;
    const int which = blockIdx.y;
    const float* __restrict__ W = (which == 0) ? Wt : (which == 1) ? Wp : Wg;
    float* __restrict__ outp = ws + (size_t)which * BN_ * D_;

    __shared__ float Xs[64][68];
    __shared__ float Wsh[64][132];

    const int tr = tid >> 4;
    const int tk = tid & 15;
    const int r0 = rb * 64;

    float acc[4][8];
#pragma unroll
    for (int i = 0; i < 4; ++i)
#pragma unroll
        for (int j = 0; j < 8; ++j) acc[i][j] = 0.f;

    for (int kc = 0; kc < 4; ++kc) {
        __syncthreads();
#pragma unroll
        for (int i = 0; i < 4; ++i) {
            int t = i * 256 + tid;
            int r = t >> 4, c4 = (t & 15) * 4;
            *(float4*)&Xs[r][c4] =
                *(const float4*)&x[(size_t)(r0 + r) * C_ + kc * 64 + c4];
        }
#pragma unroll
        for (int i = 0; i < 8; ++i) {
            int t = i * 256 + tid;
            int r = t >> 5, c4 = (t & 31) * 4;
            *(float4*)&Wsh[r][c4] =
                *(const float4*)&W[(size_t)(kc * 64 + r) * D_ + c4];
        }
        __syncthreads();

        for (int k4 = 0; k4 < 64; k4 += 4) {
            float4 a[4];
#pragma unroll
            for (int i = 0; i < 4; ++i)
                a[i] = *(const float4*)&Xs[tr + 16 * i][k4];
#pragma unroll
            for (int kk = 0; kk < 4; ++kk) {
                const float4 b0 = *(const float4*)&Wsh[k4 + kk][tk * 8];
                const float4 b1 = *(const float4*)&Wsh[k4 + kk][tk * 8 + 4];
#pragma unroll
                for (int i = 0; i < 4; ++i) {
                    const float av = (kk == 0) ? a[i].x : (kk == 1) ? a[i].y
                                    : (kk == 2) ? a[i].z : a[i].w;
                    acc[i][0] += av * b0.x; acc[i][1] += av * b0.y;
                    acc[i][2] += av * b0.z; acc[i][3] += av * b0.w;
                    acc[i][4] += av * b1.x; acc[i][5] += av * b1.y;
                    acc[i][6] += av * b1.z; acc[i][7] += av * b1.w;
                }
            }
        }
    }
#pragma unroll
    for (int i = 0; i < 4; ++i) {
        float* orow = outp + (size_t)(r0 + tr + 16 * i) * D_ + tk * 8;
        float4 o0, o1;
        o0.x = acc[i][0]; o0.y = acc[i][1]; o0.z = acc[i][2]; o0.w = acc[i][3];
        o1.x = acc[i][4]; o1.y = acc[i][5]; o1.z = acc[i][6]; o1.w = acc[i][7];
        *(float4*)&orow[0] = o0;
        *(float4*)&orow[4] = o1;
    }
}

// ------- pool: maxpool(2,1) -> pphi fp16 [b][m][d], pgT fp16 [b][d][m] -------
// grid (N_/64, B_), block 256. LDS = 17,408 B.
__global__ __launch_bounds__(256) void pool_kernel(
    const float* __restrict__ phi, const float* __restrict__ g,
    half_t* __restrict__ pphi, half_t* __restrict__ pgT)
{
    const int tid = threadIdx.x;
    const int t0 = blockIdx.x * 64;
    const int b = blockIdx.y;
    const float* __restrict__ pb = phi + (size_t)b * N_ * D_;
    const float* __restrict__ gb = g + (size_t)b * N_ * D_;

    __shared__ half_t Gs[64][136];

    {
        const int r = tid >> 2;
        const int cc = (tid & 3) * 32;
        const int m0 = t0 + r;
        const int m1 = (m0 + 1 < N_) ? m0 + 1 : m0;
        float pv[32], gv[32];
#pragma unroll
        for (int j = 0; j < 8; ++j) {
            float4 a  = *(const float4*)&pb[(size_t)m0 * D_ + cc + j * 4];
            float4 a2 = *(const float4*)&pb[(size_t)m1 * D_ + cc + j * 4];
            float4 v  = *(const float4*)&gb[(size_t)m0 * D_ + cc + j * 4];
            float4 v2 = *(const float4*)&gb[(size_t)m1 * D_ + cc + j * 4];
            pv[j*4+0] = fmaxf(a.x, a2.x); pv[j*4+1] = fmaxf(a.y, a2.y);
            pv[j*4+2] = fmaxf(a.z, a2.z); pv[j*4+3] = fmaxf(a.w, a2.w);
            gv[j*4+0] = fmaxf(v.x, v2.x); gv[j*4+1] = fmaxf(v.y, v2.y);
            gv[j*4+2] = fmaxf(v.z, v2.z); gv[j*4+3] = fmaxf(v.w, v2.w);
        }
        half8 hp[4];
#pragma unroll
        for (int j = 0; j < 32; ++j) {
            hp[j >> 3][j & 7] = (half_t)pv[j];
            Gs[r][cc + j] = (half_t)gv[j];
        }
        half8* dst = (half8*)&pphi[((size_t)b * N_ + m0) * D_ + cc];
#pragma unroll
        for (int j = 0; j < 4; ++j) dst[j] = hp[j];
    }
    __syncthreads();
    {
        const int d = tid >> 1;
        const int k2 = (tid & 1) * 32;
        half8 hb[4];
#pragma unroll
        for (int j = 0; j < 32; ++j) hb[j >> 3][j & 7] = Gs[k2 + j][d];
        half8* gdst = (half8*)&pgT[(size_t)b * D_ * N_ + (size_t)d * N_ + t0 + k2];
#pragma unroll
        for (int j = 0; j < 4; ++j) gdst[j] = hb[j];
    }
}

// ---------------- MFMA flash attention ----------------
// grid (N_/128, KSPLIT, B_) = (32,4,4) = 512 blocks, 256 thr (2 blocks/CU).
// LDS = 54,272 B. Q (theta) split fp16 hi/lo in registers; K/Gt/P in LDS.
__global__ __launch_bounds__(256, 2) void attn_kernel(
    const float* __restrict__ theta, const half_t* __restrict__ pphi,
    const half_t* __restrict__ pgT, half_t* __restrict__ ypart,
    float* __restrict__ mstat, float* __restrict__ lstat)
{
    const int tid = threadIdx.x;
    const int lane = tid & 63;
    const int w = tid >> 6;          // wave 0..3 -> queries w*32..w*32+31
    const int lm = lane & 15;
    const int lq = lane >> 4;
    const int qt = blockIdx.x, ks = blockIdx.y, b = blockIdx.z;
    const int q0 = qt * 128;

    __shared__ half_t Ks[64][136];   // K tile  [key][d]
    __shared__ half_t Gts[128][72];  // G tile  [d][key]
    __shared__ half_t Ps[128][72];   // P       [query][key]

    const half_t* __restrict__ Kb = pphi + (size_t)b * N_ * D_;
    const half_t* __restrict__ Gb = pgT + (size_t)b * D_ * N_;

    // Q fragments: A[m=lm][k=lq*8+j], rows q0 + w*32 + rb*16 + lm, split hi/lo
    half8 qhi[2][4], qlo[2][4];
#pragma unroll
    for (int rb = 0; rb < 2; ++rb) {
        const float* tr_ = theta + ((size_t)b * N_ + q0 + w * 32 + rb * 16 + lm) * D_;
#pragma unroll
        for (int c = 0; c < 4; ++c) {
            const float* p = tr_ + c * 32 + lq * 8;
            float4 v0 = *(const float4*)p;
            float4 v1 = *(const float4*)(p + 4);
            float vv[8] = {v0.x, v0.y, v0.z, v0.w, v1.x, v1.y, v1.z, v1.w};
#pragma unroll
            for (int j = 0; j < 8; ++j) {
                half_t h = (half_t)vv[j];
                qhi[rb][c][j] = h;
                qlo[rb][c][j] = (half_t)(vv[j] - (float)h);
            }
        }
    }

    float m_r[2][4], l_r[2][4];
#pragma unroll
    for (int rb = 0; rb < 2; ++rb)
#pragma unroll
        for (int r = 0; r < 4; ++r) { m_r[rb][r] = -1e30f; l_r[rb][r] = 0.f; }
    f32x4 yacc[2][8];
#pragma unroll
    for (int rb = 0; rb < 2; ++rb)
#pragma unroll
        for (int db = 0; db < 8; ++db)
#pragma unroll
            for (int r = 0; r < 4; ++r) yacc[rb][db][r] = 0.f;

    for (int kt = 0; kt < KTILES; ++kt) {
        const int k0 = ks * KEYS_PER_SPLIT + kt * 64;
        __syncthreads();   // prev PV reads of Ks/Gts done
        {
            const int r = tid >> 2, cc = (tid & 3) * 32;
            const float4* src = (const float4*)(Kb + (size_t)(k0 + r) * D_ + cc);
            float4 a0 = src[0], a1 = src[1], a2 = src[2], a3 = src[3];
            float4* dst = (float4*)&Ks[r][cc];
            dst[0] = a0; dst[1] = a1; dst[2] = a2; dst[3] = a3;
            const int d = tid >> 1, kc = (tid & 1) * 32;
            const float4* gsrc = (const float4*)(Gb + (size_t)d * N_ + k0 + kc);
            float4 g0 = gsrc[0], g1 = gsrc[1], g2 = gsrc[2], g3 = gsrc[3];
            float4* gdst = (float4*)&Gts[d][kc];
            gdst[0] = g0; gdst[1] = g1; gdst[2] = g2; gdst[3] = g3;
        }
        __syncthreads();

        // QK^T: C[q][key], B-frag B[k=d][n=key] = Ks[key][d] rows
        f32x4 sc[2][4];
#pragma unroll
        for (int rb = 0; rb < 2; ++rb)
#pragma unroll
            for (int kb = 0; kb < 4; ++kb)
#pragma unroll
                for (int r = 0; r < 4; ++r) sc[rb][kb][r] = 0.f;
#pragma unroll
        for (int kb = 0; kb < 4; ++kb) {
#pragma unroll
            for (int c = 0; c < 4; ++c) {
                half8 kf = *(const half8*)&Ks[kb * 16 + lm][c * 32 + lq * 8];
#pragma unroll
                for (int rb = 0; rb < 2; ++rb) {
                    sc[rb][kb] = MFMA16x16x32(qlo[rb][c], kf, sc[rb][kb]);
                    sc[rb][kb] = MFMA16x16x32(qhi[rb][c], kf, sc[rb][kb]);
                }
            }
        }
        // mask padded key 4095
#pragma unroll
        for (int kb = 0; kb < 4; ++kb) {
            if (k0 + kb * 16 + lm >= M_) {
#pragma unroll
                for (int r = 0; r < 4; ++r) { sc[0][kb][r] = -1e30f; sc[1][kb][r] = -1e30f; }
            }
        }
        // online softmax (row = lq*4+r within rowblock; reduce across 16 key-lanes)
        float alpha[2][4];
#pragma unroll
        for (int rb = 0; rb < 2; ++rb) {
#pragma unroll
            for (int r = 0; r < 4; ++r) {
                float mt = fmaxf(fmaxf(sc[rb][0][r], sc[rb][1][r]),
                                 fmaxf(sc[rb][2][r], sc[rb][3][r]));
#pragma unroll
                for (int off = 1; off < 16; off <<= 1)
                    mt = fmaxf(mt, __shfl_xor(mt, off, 16));
                const float mnew = fmaxf(m_r[rb][r], mt);
                alpha[rb][r] = __expf(m_r[rb][r] - mnew);
                m_r[rb][r] = mnew;
                float rs = 0.f;
#pragma unroll
                for (int kb = 0; kb < 4; ++kb) {
                    float pz = __expf(sc[rb][kb][r] - mnew);
                    sc[rb][kb][r] = pz;
                    rs += pz;
                }
#pragma unroll
                for (int off = 1; off < 16; off <<= 1)
                    rs += __shfl_xor(rs, off, 16);
                l_r[rb][r] = l_r[rb][r] * alpha[rb][r] + rs;
            }
        }
        // stage P (each wave writes/reads only its own rows -> no barrier)
#pragma unroll
        for (int rb = 0; rb < 2; ++rb)
#pragma unroll
            for (int kb = 0; kb < 4; ++kb)
#pragma unroll
                for (int r = 0; r < 4; ++r)
                    Ps[w * 32 + rb * 16 + lq * 4 + r][kb * 16 + lm] =
                        (half_t)sc[rb][kb][r];
        // rescale accumulator
#pragma unroll
        for (int rb = 0; rb < 2; ++rb)
#pragma unroll
            for (int db = 0; db < 8; ++db)
#pragma unroll
                for (int r = 0; r < 4; ++r) yacc[rb][db][r] *= alpha[rb][r];
        // PV: A = P rows, B-frag B[k=key][n=d] = Gts[d][key] rows
        half8 pf[2][2];
#pragma unroll
        for (int rb = 0; rb < 2; ++rb)
#pragma unroll
            for (int c2 = 0; c2 < 2; ++c2)
                pf[rb][c2] = *(const half8*)&Ps[w * 32 + rb * 16 + lm][c2 * 32 + lq * 8];
#pragma unroll
        for (int db = 0; db < 8; ++db) {
#pragma unroll
            for (int c2 = 0; c2 < 2; ++c2) {
                half8 gf = *(const half8*)&Gts[db * 16 + lm][c2 * 32 + lq * 8];
                yacc[0][db] = MFMA16x16x32(pf[0][c2], gf, yacc[0][db]);
                yacc[1][db] = MFMA16x16x32(pf[1][c2], gf, yacc[1][db]);
            }
        }
    }

    // epilogue: unnormalized y partial (fp16) + (m,l) stats
    half_t* yp = ypart + ((size_t)ks * BN_ + (size_t)b * N_) * D_;
#pragma unroll
    for (int rb = 0; rb < 2; ++rb)
#pragma unroll
        for (int db = 0; db < 8; ++db)
#pragma unroll
            for (int r = 0; r < 4; ++r)
                yp[(size_t)(q0 + w * 32 + rb * 16 + lq * 4 + r) * D_ + db * 16 + lm] =
                    (half_t)yacc[rb][db][r];
    if (lm == 0) {
#pragma unroll
        for (int rb = 0; rb < 2; ++rb)
#pragma unroll
            for (int r = 0; r < 4; ++r) {
                const int row = q0 + w * 32 + rb * 16 + lq * 4 + r;
                mstat[(size_t)ks * BN_ + (size_t)b * N_ + row] = m_r[rb][r];
                lstat[(size_t)ks * BN_ + (size_t)b * N_ + row] = l_r[rb][r];
            }
    }
}

// ---------------- final: merge 4 partials, z = x + y @ Wf ----------------
// grid (BN_/64, C_/64), block 256. LDS = 35,840 B.
__global__ __launch_bounds__(256) void final_kernel(
    const half_t* __restrict__ ypart, const float* __restrict__ mstat,
    const float* __restrict__ lstat, const float* __restrict__ x,
    const float* __restrict__ Wf, float* __restrict__ out)
{
    const int tid = threadIdx.x;
    const int rblk = blockIdx.x;
    const int cb = blockIdx.y;
    const int r0 = rblk * 64, c0 = cb * 64;

    __shared__ float Ys[64][68];
    __shared__ float Wfs[64][68];
    __shared__ float scl[4][64];

    if (tid < 64) {
        const int row = r0 + tid;
        float mv[4], lv[4], wv[4];
        float M = -1e30f;
#pragma unroll
        for (int s = 0; s < 4; ++s) {
            mv[s] = mstat[(size_t)s * BN_ + row];
            lv[s] = lstat[(size_t)s * BN_ + row];
            M = fmaxf(M, mv[s]);
        }
        float lsum = 0.f;
#pragma unroll
        for (int s = 0; s < 4; ++s) { wv[s] = __expf(mv[s] - M); lsum += wv[s] * lv[s]; }
        const float inv = 1.f / lsum;
#pragma unroll
        for (int s = 0; s < 4; ++s) scl[s][tid] = wv[s] * inv;
    }
    __syncthreads();

    const int tr = tid >> 4;
    const int tk = tid & 15;

    float acc[4][4];
#pragma unroll
    for (int i = 0; i < 4; ++i)
#pragma unroll
        for (int j = 0; j < 4; ++j) acc[i][j] = 0.f;

    for (int kc = 0; kc < 2; ++kc) {
        if (kc) __syncthreads();
#pragma unroll
        for (int i = 0; i < 4; ++i) {
            int t = i * 256 + tid;
            int r = t >> 4, c4 = (t & 15) * 4;
            const size_t ybase = (size_t)(r0 + r) * D_ + kc * 64 + c4;
            const float s0 = scl[0][r], s1 = scl[1][r], s2 = scl[2][r], s3 = scl[3][r];
            half4 y0 = *(const half4*)&ypart[0 * (size_t)BN_ * D_ + ybase];
            half4 y1 = *(const half4*)&ypart[1 * (size_t)BN_ * D_ + ybase];
            half4 y2 = *(const half4*)&ypart[2 * (size_t)BN_ * D_ + ybase];
            half4 y3 = *(const half4*)&ypart[3 * (size_t)BN_ * D_ + ybase];
            float4 ym;
            ym.x = s0*(float)y0[0] + s1*(float)y1[0] + s2*(float)y2[0] + s3*(float)y3[0];
            ym.y = s0*(float)y0[1] + s1*(float)y1[1] + s2*(float)y2[1] + s3*(float)y3[1];
            ym.z = s0*(float)y0[2] + s1*(float)y1[2] + s2*(float)y2[2] + s3*(float)y3[2];
            ym.w = s0*(float)y0[3] + s1*(float)y1[3] + s2*(float)y2[3] + s3*(float)y3[3];
            *(float4*)&Ys[r][c4] = ym;
            *(float4*)&Wfs[r][c4] =
                *(const float4*)&Wf[(size_t)(kc * 64 + r) * C_ + c0 + c4];
        }
        __syncthreads();

        for (int k4 = 0; k4 < 64; k4 += 4) {
            float4 a[4];
#pragma unroll
            for (int i = 0; i < 4; ++i)
                a[i] = *(const float4*)&Ys[tr + 16 * i][k4];
#pragma unroll
            for (int kk = 0; kk < 4; ++kk) {
                const float4 bv = *(const float4*)&Wfs[k4 + kk][tk * 4];
#pragma unroll
                for (int i = 0; i < 4; ++i) {
                    const float av = (kk == 0) ? a[i].x : (kk == 1) ? a[i].y
                                    : (kk == 2) ? a[i].z : a[i].w;
                    acc[i][0] += av * bv.x; acc[i][1] += av * bv.y;
                    acc[i][2] += av * bv.z; acc[i][3] += av * bv.w;
                }
            }
        }
    }
#pragma unroll
    for (int i = 0; i < 4; ++i) {
        const int r = r0 + tr + 16 * i;
        const int c = c0 + tk * 4;
        const float4 xr = *(const float4*)&x[(size_t)r * C_ + c];
        float4 o;
        o.x = acc[i][0] + xr.x; o.y = acc[i][1] + xr.y;
        o.z = acc[i][2] + xr.z; o.w = acc[i][3] + xr.w;
        *(float4*)&out[(size_t)r * C_ + c] = o;
    }
}

extern "C" void kernel_launch(void* const* d_in, const int* in_sizes, int n_in,
                              void* d_out, int out_size, void* d_ws, size_t ws_size,
                              hipStream_t stream)
{
    const float* x  = (const float*)d_in[0];
    const float* Wt = (const float*)d_in[1];
    const float* Wp = (const float*)d_in[2];
    const float* Wg = (const float*)d_in[3];
    const float* Wf = (const float*)d_in[4];
    float* out = (float*)d_out;

    // ws (fp32 words): theta | phi_raw | g_raw | pphi+pgT (fp16) | stats
    // ypart (fp16, 4 splits x 4 MB = 16 MB) aliases phi_raw+g_raw. Total ~34 MB.
    const size_t SEG = (size_t)BN_ * D_;   // 2,097,152
    float* ws    = (float*)d_ws;
    float* theta = ws;
    float* phi_r = ws + 1 * SEG;
    float* g_r   = ws + 2 * SEG;
    half_t* pphi = (half_t*)(ws + 3 * SEG);
    half_t* pgT  = (half_t*)(ws + 3 * SEG + SEG / 2);
    float* mstat = ws + 4 * SEG;
    float* lstat = ws + 4 * SEG + (size_t)KSPLIT * BN_;
    half_t* ypart = (half_t*)(ws + 1 * SEG);   // overwrites phi_r/g_r after pool

    proj_kernel<<<dim3(BN_ / 64, 3), 256, 0, stream>>>(x, Wt, Wp, Wg, ws);
    pool_kernel<<<dim3(N_ / 64, B_), 256, 0, stream>>>(phi_r, g_r, pphi, pgT);
    attn_kernel<<<dim3(N_ / 128, KSPLIT, B_), 256, 0, stream>>>(
        theta, pphi, pgT, ypart, mstat, lstat);
    final_kernel<<<dim3(BN_ / 64, C_ / 64), 256, 0, stream>>>(
        ypart, mstat, lstat, x, Wf, out);
}

// Round 5
// 232.415 us; speedup vs baseline: 3.4125x; 1.0089x over previous
//
#include <hip/hip_runtime.h>

#define B_  4
#define N_  4096
#define C_  256
#define D_  128
#define M_  4095
#define BN_ (B_ * N_)
#define KSPLIT 4
#define KEYS_PER_SPLIT (N_ / KSPLIT)   // 1024
#define KTILES (KEYS_PER_SPLIT / 64)   // 16

typedef _Float16 half_t;
typedef __attribute__((ext_vector_type(8))) _Float16 half8;
typedef __attribute__((ext_vector_type(4))) float f32x4;

#define MFMA16x16x32(A, B, C) __builtin_amdgcn_mfma_f32_16x16x32_f16(A, B, C, 0, 0, 0)

// ---- prep: transpose weights into B-fragment layouts (runs once, tiny) ----
// grid (128, 4): y=0..2 -> WT_hi/WT_lo[which][d][c] from {Wt,Wp,Wg}[c][d];
//                y=3    -> WfT[c][d] (fp16) from Wf[d][c].
__global__ __launch_bounds__(256) void prep_kernel(
    const float* __restrict__ Wt, const float* __restrict__ Wp,
    const float* __restrict__ Wg, const float* __restrict__ Wf,
    half_t* __restrict__ WT_hi, half_t* __restrict__ WT_lo,
    half_t* __restrict__ WfT)
{
    const int idx = blockIdx.x * 256 + threadIdx.x;   // 0..32767
    const int wsel = blockIdx.y;
    if (wsel < 3) {
        const float* __restrict__ W = (wsel == 0) ? Wt : (wsel == 1) ? Wp : Wg;
        const int d = idx >> 8, c = idx & 255;
        const float v = W[(size_t)c * D_ + d];
        const half_t h = (half_t)v;
        WT_hi[(size_t)wsel * 32768 + idx] = h;
        WT_lo[(size_t)wsel * 32768 + idx] = (half_t)(v - (float)h);
    } else {
        const int c = idx >> 7, d = idx & 127;
        WfT[idx] = (half_t)Wf[(size_t)d * C_ + c];
    }
}

// ---- proj (MFMA, 3-term split ~= fp32): theta/phi/g = x @ W ----
// grid (BN_/128, 3), block 256 (4 waves). LDS = 40,960 B.
__global__ __launch_bounds__(256) void proj_kernel(
    const float* __restrict__ x, const half_t* __restrict__ WT_hi,
    const half_t* __restrict__ WT_lo, float* __restrict__ ws)
{
    const int tid = threadIdx.x;
    const int lane = tid & 63;
    const int w = tid >> 6;
    const int lm = lane & 15;
    const int lq = lane >> 4;
    const int r0 = blockIdx.x * 128;
    const int which = blockIdx.y;
    float* __restrict__ outp = ws + (size_t)which * BN_ * D_;
    const half_t* __restrict__ Wh_g = WT_hi + (size_t)which * 32768;
    const half_t* __restrict__ Wl_g = WT_lo + (size_t)which * 32768;

    __shared__ half_t Xh[128][40], Xl[128][40];
    __shared__ half_t Whl[128][40], Wll[128][40];

    f32x4 acc[2][8];
#pragma unroll
    for (int rb = 0; rb < 2; ++rb)
#pragma unroll
        for (int nb = 0; nb < 8; ++nb)
#pragma unroll
            for (int r = 0; r < 4; ++r) acc[rb][nb][r] = 0.f;

    const int sr = tid >> 1;          // 0..127
    const int cL = (tid & 1) * 16;    // 0 or 16

    for (int kc = 0; kc < 8; ++kc) {  // C=256 in chunks of 32
        __syncthreads();
        {   // stage x chunk -> hi/lo fp16
            const float* xs = x + (size_t)(r0 + sr) * C_ + kc * 32 + cL;
            float vv[16];
            float4 v0 = *(const float4*)&xs[0], v1 = *(const float4*)&xs[4];
            float4 v2 = *(const float4*)&xs[8], v3 = *(const float4*)&xs[12];
            vv[0]=v0.x; vv[1]=v0.y; vv[2]=v0.z; vv[3]=v0.w;
            vv[4]=v1.x; vv[5]=v1.y; vv[6]=v1.z; vv[7]=v1.w;
            vv[8]=v2.x; vv[9]=v2.y; vv[10]=v2.z; vv[11]=v2.w;
            vv[12]=v3.x; vv[13]=v3.y; vv[14]=v3.z; vv[15]=v3.w;
            half8 hi[2], lo[2];
#pragma unroll
            for (int j = 0; j < 16; ++j) {
                half_t h = (half_t)vv[j];
                hi[j >> 3][j & 7] = h;
                lo[j >> 3][j & 7] = (half_t)(vv[j] - (float)h);
            }
            *(half8*)&Xh[sr][cL] = hi[0]; *(half8*)&Xh[sr][cL + 8] = hi[1];
            *(half8*)&Xl[sr][cL] = lo[0]; *(half8*)&Xl[sr][cL + 8] = lo[1];
            // stage W chunk (already hi/lo fp16 in [d][c] layout)
            const half_t* wh = Wh_g + (size_t)sr * 256 + kc * 32 + cL;
            const half_t* wl = Wl_g + (size_t)sr * 256 + kc * 32 + cL;
            *(half8*)&Whl[sr][cL] = *(const half8*)&wh[0];
            *(half8*)&Whl[sr][cL + 8] = *(const half8*)&wh[8];
            *(half8*)&Wll[sr][cL] = *(const half8*)&wl[0];
            *(half8*)&Wll[sr][cL + 8] = *(const half8*)&wl[8];
        }
        __syncthreads();

        half8 ah[2], al[2];
#pragma unroll
        for (int rb = 0; rb < 2; ++rb) {
            ah[rb] = *(const half8*)&Xh[w * 32 + rb * 16 + lm][lq * 8];
            al[rb] = *(const half8*)&Xl[w * 32 + rb * 16 + lm][lq * 8];
        }
#pragma unroll
        for (int nb = 0; nb < 8; ++nb) {
            half8 bh = *(const half8*)&Whl[nb * 16 + lm][lq * 8];
            half8 bl = *(const half8*)&Wll[nb * 16 + lm][lq * 8];
#pragma unroll
            for (int rb = 0; rb < 2; ++rb) {
                acc[rb][nb] = MFMA16x16x32(ah[rb], bh, acc[rb][nb]);
                acc[rb][nb] = MFMA16x16x32(al[rb], bh, acc[rb][nb]);
                acc[rb][nb] = MFMA16x16x32(ah[rb], bl, acc[rb][nb]);
            }
        }
    }
#pragma unroll
    for (int rb = 0; rb < 2; ++rb)
#pragma unroll
        for (int nb = 0; nb < 8; ++nb)
#pragma unroll
            for (int r = 0; r < 4; ++r)
                outp[(size_t)(r0 + w * 32 + rb * 16 + lq * 4 + r) * D_ +
                     nb * 16 + lm] = acc[rb][nb][r];
}

// ------- pool: maxpool(2,1) -> pphi fp16 [b][m][d], pgT fp16 [b][d][m] -------
__global__ __launch_bounds__(256) void pool_kernel(
    const float* __restrict__ phi, const float* __restrict__ g,
    half_t* __restrict__ pphi, half_t* __restrict__ pgT)
{
    const int tid = threadIdx.x;
    const int t0 = blockIdx.x * 64;
    const int b = blockIdx.y;
    const float* __restrict__ pb = phi + (size_t)b * N_ * D_;
    const float* __restrict__ gb = g + (size_t)b * N_ * D_;

    __shared__ half_t Gs[64][136];

    {
        const int r = tid >> 2;
        const int cc = (tid & 3) * 32;
        const int m0 = t0 + r;
        const int m1 = (m0 + 1 < N_) ? m0 + 1 : m0;
        float pv[32], gv[32];
#pragma unroll
        for (int j = 0; j < 8; ++j) {
            float4 a  = *(const float4*)&pb[(size_t)m0 * D_ + cc + j * 4];
            float4 a2 = *(const float4*)&pb[(size_t)m1 * D_ + cc + j * 4];
            float4 v  = *(const float4*)&gb[(size_t)m0 * D_ + cc + j * 4];
            float4 v2 = *(const float4*)&gb[(size_t)m1 * D_ + cc + j * 4];
            pv[j*4+0] = fmaxf(a.x, a2.x); pv[j*4+1] = fmaxf(a.y, a2.y);
            pv[j*4+2] = fmaxf(a.z, a2.z); pv[j*4+3] = fmaxf(a.w, a2.w);
            gv[j*4+0] = fmaxf(v.x, v2.x); gv[j*4+1] = fmaxf(v.y, v2.y);
            gv[j*4+2] = fmaxf(v.z, v2.z); gv[j*4+3] = fmaxf(v.w, v2.w);
        }
        half8 hp[4];
#pragma unroll
        for (int j = 0; j < 32; ++j) {
            hp[j >> 3][j & 7] = (half_t)pv[j];
            Gs[r][cc + j] = (half_t)gv[j];
        }
        half8* dst = (half8*)&pphi[((size_t)b * N_ + m0) * D_ + cc];
#pragma unroll
        for (int j = 0; j < 4; ++j) dst[j] = hp[j];
    }
    __syncthreads();
    {
        const int d = tid >> 1;
        const int k2 = (tid & 1) * 32;
        half8 hb[4];
#pragma unroll
        for (int j = 0; j < 32; ++j) hb[j >> 3][j & 7] = Gs[k2 + j][d];
        half8* gdst = (half8*)&pgT[(size_t)b * D_ * N_ + (size_t)d * N_ + t0 + k2];
#pragma unroll
        for (int j = 0; j < 4; ++j) gdst[j] = hb[j];
    }
}

// ---------------- MFMA flash attention (register-prefetched staging) --------
// grid (N_/128, KSPLIT, B_) = 512 blocks, 256 thr. LDS = 54,272 B.
__global__ __launch_bounds__(256, 2) void attn_kernel(
    const float* __restrict__ theta, const half_t* __restrict__ pphi,
    const half_t* __restrict__ pgT, half_t* __restrict__ ypart,
    float* __restrict__ mstat, float* __restrict__ lstat)
{
    const int tid = threadIdx.x;
    const int lane = tid & 63;
    const int w = tid >> 6;
    const int lm = lane & 15;
    const int lq = lane >> 4;
    const int qt = blockIdx.x, ks = blockIdx.y, b = blockIdx.z;
    const int q0 = qt * 128;

    __shared__ half_t Ks[64][136];   // K tile  [key][d]
    __shared__ half_t Gts[128][72];  // G tile  [d][key]
    __shared__ half_t Ps[128][72];   // P       [query][key]

    const half_t* __restrict__ Kb = pphi + (size_t)b * N_ * D_;
    const half_t* __restrict__ Gb = pgT + (size_t)b * D_ * N_;

    // staging thread mapping
    const int skr = tid >> 2, skc = (tid & 3) * 32;   // K: row, col
    const int sgd = tid >> 1, sgk = (tid & 1) * 32;   // G: d-row, key-col

    // Q fragments: rows q0 + w*32 + rb*16 + lm, split hi/lo
    half8 qhi[2][4], qlo[2][4];
#pragma unroll
    for (int rb = 0; rb < 2; ++rb) {
        const float* tr_ = theta + ((size_t)b * N_ + q0 + w * 32 + rb * 16 + lm) * D_;
#pragma unroll
        for (int c = 0; c < 4; ++c) {
            const float* p = tr_ + c * 32 + lq * 8;
            float4 v0 = *(const float4*)p;
            float4 v1 = *(const float4*)(p + 4);
            float vv[8] = {v0.x, v0.y, v0.z, v0.w, v1.x, v1.y, v1.z, v1.w};
#pragma unroll
            for (int j = 0; j < 8; ++j) {
                half_t h = (half_t)vv[j];
                qhi[rb][c][j] = h;
                qlo[rb][c][j] = (half_t)(vv[j] - (float)h);
            }
        }
    }

    float m_r[2][4], l_r[2][4];
#pragma unroll
    for (int rb = 0; rb < 2; ++rb)
#pragma unroll
        for (int r = 0; r < 4; ++r) { m_r[rb][r] = -1e30f; l_r[rb][r] = 0.f; }
    f32x4 yacc[2][8];
#pragma unroll
    for (int rb = 0; rb < 2; ++rb)
#pragma unroll
        for (int db = 0; db < 8; ++db)
#pragma unroll
            for (int r = 0; r < 4; ++r) yacc[rb][db][r] = 0.f;

    // prefetch ktile 0 into registers
    float4 kr[4], gr[4];
    {
        const int k0 = ks * KEYS_PER_SPLIT;
        const float4* src = (const float4*)(Kb + (size_t)(k0 + skr) * D_ + skc);
        kr[0] = src[0]; kr[1] = src[1]; kr[2] = src[2]; kr[3] = src[3];
        const float4* gsrc = (const float4*)(Gb + (size_t)sgd * N_ + k0 + sgk);
        gr[0] = gsrc[0]; gr[1] = gsrc[1]; gr[2] = gsrc[2]; gr[3] = gsrc[3];
    }

    for (int kt = 0; kt < KTILES; ++kt) {
        const int k0 = ks * KEYS_PER_SPLIT + kt * 64;
        __syncthreads();   // prev compute done reading Ks/Gts
        {   // commit prefetched tile to LDS
            float4* dst = (float4*)&Ks[skr][skc];
            dst[0] = kr[0]; dst[1] = kr[1]; dst[2] = kr[2]; dst[3] = kr[3];
            float4* gdst = (float4*)&Gts[sgd][sgk];
            gdst[0] = gr[0]; gdst[1] = gr[1]; gdst[2] = gr[2]; gdst[3] = gr[3];
        }
        __syncthreads();
        if (kt + 1 < KTILES) {   // prefetch next tile (latency hidden by compute)
            const int kn = k0 + 64;
            const float4* src = (const float4*)(Kb + (size_t)(kn + skr) * D_ + skc);
            kr[0] = src[0]; kr[1] = src[1]; kr[2] = src[2]; kr[3] = src[3];
            const float4* gsrc = (const float4*)(Gb + (size_t)sgd * N_ + kn + sgk);
            gr[0] = gsrc[0]; gr[1] = gsrc[1]; gr[2] = gsrc[2]; gr[3] = gsrc[3];
        }

        // QK^T
        f32x4 sc[2][4];
#pragma unroll
        for (int rb = 0; rb < 2; ++rb)
#pragma unroll
            for (int kb = 0; kb < 4; ++kb)
#pragma unroll
                for (int r = 0; r < 4; ++r) sc[rb][kb][r] = 0.f;
#pragma unroll
        for (int kb = 0; kb < 4; ++kb) {
#pragma unroll
            for (int c = 0; c < 4; ++c) {
                half8 kf = *(const half8*)&Ks[kb * 16 + lm][c * 32 + lq * 8];
#pragma unroll
                for (int rb = 0; rb < 2; ++rb) {
                    sc[rb][kb] = MFMA16x16x32(qlo[rb][c], kf, sc[rb][kb]);
                    sc[rb][kb] = MFMA16x16x32(qhi[rb][c], kf, sc[rb][kb]);
                }
            }
        }
        // mask padded key 4095
#pragma unroll
        for (int kb = 0; kb < 4; ++kb) {
            if (k0 + kb * 16 + lm >= M_) {
#pragma unroll
                for (int r = 0; r < 4; ++r) { sc[0][kb][r] = -1e30f; sc[1][kb][r] = -1e30f; }
            }
        }
        // online softmax
        float alpha[2][4];
#pragma unroll
        for (int rb = 0; rb < 2; ++rb) {
#pragma unroll
            for (int r = 0; r < 4; ++r) {
                float mt = fmaxf(fmaxf(sc[rb][0][r], sc[rb][1][r]),
                                 fmaxf(sc[rb][2][r], sc[rb][3][r]));
#pragma unroll
                for (int off = 1; off < 16; off <<= 1)
                    mt = fmaxf(mt, __shfl_xor(mt, off, 16));
                const float mnew = fmaxf(m_r[rb][r], mt);
                alpha[rb][r] = __expf(m_r[rb][r] - mnew);
                m_r[rb][r] = mnew;
                float rs = 0.f;
#pragma unroll
                for (int kb = 0; kb < 4; ++kb) {
                    float pz = __expf(sc[rb][kb][r] - mnew);
                    sc[rb][kb][r] = pz;
                    rs += pz;
                }
#pragma unroll
                for (int off = 1; off < 16; off <<= 1)
                    rs += __shfl_xor(rs, off, 16);
                l_r[rb][r] = l_r[rb][r] * alpha[rb][r] + rs;
            }
        }
        // stage P (wave-private rows: no barrier)
#pragma unroll
        for (int rb = 0; rb < 2; ++rb)
#pragma unroll
            for (int kb = 0; kb < 4; ++kb)
#pragma unroll
                for (int r = 0; r < 4; ++r)
                    Ps[w * 32 + rb * 16 + lq * 4 + r][kb * 16 + lm] =
                        (half_t)sc[rb][kb][r];
        // rescale accumulator
#pragma unroll
        for (int rb = 0; rb < 2; ++rb)
#pragma unroll
            for (int db = 0; db < 8; ++db)
#pragma unroll
                for (int r = 0; r < 4; ++r) yacc[rb][db][r] *= alpha[rb][r];
        // PV
        half8 pf[2][2];
#pragma unroll
        for (int rb = 0; rb < 2; ++rb)
#pragma unroll
            for (int c2 = 0; c2 < 2; ++c2)
                pf[rb][c2] = *(const half8*)&Ps[w * 32 + rb * 16 + lm][c2 * 32 + lq * 8];
#pragma unroll
        for (int db = 0; db < 8; ++db) {
#pragma unroll
            for (int c2 = 0; c2 < 2; ++c2) {
                half8 gf = *(const half8*)&Gts[db * 16 + lm][c2 * 32 + lq * 8];
                yacc[0][db] = MFMA16x16x32(pf[0][c2], gf, yacc[0][db]);
                yacc[1][db] = MFMA16x16x32(pf[1][c2], gf, yacc[1][db]);
            }
        }
    }

    // epilogue: unnormalized y partial (fp16) + (m,l) stats
    half_t* yp = ypart + ((size_t)ks * BN_ + (size_t)b * N_) * D_;
#pragma unroll
    for (int rb = 0; rb < 2; ++rb)
#pragma unroll
        for (int db = 0; db < 8; ++db)
#pragma unroll
            for (int r = 0; r < 4; ++r)
                yp[(size_t)(q0 + w * 32 + rb * 16 + lq * 4 + r) * D_ + db * 16 + lm] =
                    (half_t)yacc[rb][db][r];
    if (lm == 0) {
#pragma unroll
        for (int rb = 0; rb < 2; ++rb)
#pragma unroll
            for (int r = 0; r < 4; ++r) {
                const int row = q0 + w * 32 + rb * 16 + lq * 4 + r;
                mstat[(size_t)ks * BN_ + (size_t)b * N_ + row] = m_r[rb][r];
                lstat[(size_t)ks * BN_ + (size_t)b * N_ + row] = l_r[rb][r];
            }
    }
}

// ---- final (MFMA): merge 4 partials, z = x + y @ Wf ----
// grid (BN_/128, 2), block 256. LDS = 38,912 B.
__global__ __launch_bounds__(256) void final_kernel(
    const half_t* __restrict__ ypart, const float* __restrict__ mstat,
    const float* __restrict__ lstat, const float* __restrict__ x,
    const half_t* __restrict__ WfT, float* __restrict__ out)
{
    const int tid = threadIdx.x;
    const int lane = tid & 63;
    const int w = tid >> 6;
    const int lm = lane & 15;
    const int lq = lane >> 4;
    const int r0 = blockIdx.x * 128;
    const int c0 = blockIdx.y * 128;

    __shared__ half_t Ys[128][72];
    __shared__ half_t Wfs[128][72];
    __shared__ float scl[4][128];

    if (tid < 128) {
        const int row = r0 + tid;
        float mv[4], lv[4], wv[4];
        float Mx = -1e30f;
#pragma unroll
        for (int s = 0; s < 4; ++s) {
            mv[s] = mstat[(size_t)s * BN_ + row];
            lv[s] = lstat[(size_t)s * BN_ + row];
            Mx = fmaxf(Mx, mv[s]);
        }
        float lsum = 0.f;
#pragma unroll
        for (int s = 0; s < 4; ++s) { wv[s] = __expf(mv[s] - Mx); lsum += wv[s] * lv[s]; }
        const float inv = 1.f / lsum;
#pragma unroll
        for (int s = 0; s < 4; ++s) scl[s][tid] = wv[s] * inv;
    }
    __syncthreads();

    f32x4 acc[2][8];
#pragma unroll
    for (int rb = 0; rb < 2; ++rb)
#pragma unroll
        for (int nb = 0; nb < 8; ++nb)
#pragma unroll
            for (int r = 0; r < 4; ++r) acc[rb][nb][r] = 0.f;

    const int sr = tid >> 1;
    const int dd = (tid & 1) * 32;

    for (int kc = 0; kc < 2; ++kc) {   // K = D = 128 in chunks of 64
        {   // merge ypart -> fp16 Ys chunk; stage WfT chunk
            const float s0 = scl[0][sr], s1 = scl[1][sr],
                        s2 = scl[2][sr], s3 = scl[3][sr];
            const size_t yb = (size_t)(r0 + sr) * D_ + kc * 64 + dd;
            half8 o[4];
#pragma unroll
            for (int q = 0; q < 4; ++q) {
                half8 y0 = *(const half8*)&ypart[0 * (size_t)BN_ * D_ + yb + q * 8];
                half8 y1 = *(const half8*)&ypart[1 * (size_t)BN_ * D_ + yb + q * 8];
                half8 y2 = *(const half8*)&ypart[2 * (size_t)BN_ * D_ + yb + q * 8];
                half8 y3 = *(const half8*)&ypart[3 * (size_t)BN_ * D_ + yb + q * 8];
#pragma unroll
                for (int j = 0; j < 8; ++j)
                    o[q][j] = (half_t)(s0 * (float)y0[j] + s1 * (float)y1[j] +
                                       s2 * (float)y2[j] + s3 * (float)y3[j]);
            }
#pragma unroll
            for (int q = 0; q < 4; ++q) *(half8*)&Ys[sr][dd + q * 8] = o[q];
            const half_t* wf = WfT + (size_t)(c0 + sr) * D_ + kc * 64 + dd;
#pragma unroll
            for (int q = 0; q < 4; ++q)
                *(half8*)&Wfs[sr][dd + q * 8] = *(const half8*)&wf[q * 8];
        }
        __syncthreads();

        half8 af[2][2];
#pragma unroll
        for (int rb = 0; rb < 2; ++rb)
#pragma unroll
            for (int k2 = 0; k2 < 2; ++k2)
                af[rb][k2] = *(const half8*)&Ys[w * 32 + rb * 16 + lm][k2 * 32 + lq * 8];
#pragma unroll
        for (int nb = 0; nb < 8; ++nb) {
#pragma unroll
            for (int k2 = 0; k2 < 2; ++k2) {
                half8 bf = *(const half8*)&Wfs[nb * 16 + lm][k2 * 32 + lq * 8];
                acc[0][nb] = MFMA16x16x32(af[0][k2], bf, acc[0][nb]);
                acc[1][nb] = MFMA16x16x32(af[1][k2], bf, acc[1][nb]);
            }
        }
        __syncthreads();   // before next-stage overwrite
    }
    // residual + store fp32
#pragma unroll
    for (int rb = 0; rb < 2; ++rb)
#pragma unroll
        for (int nb = 0; nb < 8; ++nb)
#pragma unroll
            for (int r = 0; r < 4; ++r) {
                const int row = r0 + w * 32 + rb * 16 + lq * 4 + r;
                const int col = c0 + nb * 16 + lm;
                out[(size_t)row * C_ + col] =
                    acc[rb][nb][r] + x[(size_t)row * C_ + col];
            }
}

extern "C" void kernel_launch(void* const* d_in, const int* in_sizes, int n_in,
                              void* d_out, int out_size, void* d_ws, size_t ws_size,
                              hipStream_t stream)
{
    const float* x  = (const float*)d_in[0];
    const float* Wt = (const float*)d_in[1];
    const float* Wp = (const float*)d_in[2];
    const float* Wg = (const float*)d_in[3];
    const float* Wf = (const float*)d_in[4];
    float* out = (float*)d_out;

    // ws (fp32 words, SEG = BN_*D_ = 2,097,152):
    //   [0] theta | [1] phi_raw | [2] g_raw | [3] pphi+pgT (fp16)
    //   [4] mstat | lstat | WT_hi | WT_lo | WfT
    //   ypart (fp16, 16 MB) aliases [1]+[2] after pool. Total 40 MB.
    const size_t SEG = (size_t)BN_ * D_;
    float* ws    = (float*)d_ws;
    float* theta = ws;
    float* phi_r = ws + 1 * SEG;
    float* g_r   = ws + 2 * SEG;
    half_t* pphi = (half_t*)(ws + 3 * SEG);
    half_t* pgT  = (half_t*)(ws + 3 * SEG + SEG / 2);
    float* seg4  = ws + 4 * SEG;
    float* mstat = seg4;                                   // 65,536 f
    float* lstat = seg4 + (size_t)KSPLIT * BN_;            // 65,536 f
    half_t* WT_hi = (half_t*)(seg4 + 2 * (size_t)KSPLIT * BN_);      // 98,304 h
    half_t* WT_lo = WT_hi + 3 * 32768;                               // 98,304 h
    half_t* WfT   = WT_lo + 3 * 32768;                               // 32,768 h
    half_t* ypart = (half_t*)(ws + 1 * SEG);

    prep_kernel<<<dim3(128, 4), 256, 0, stream>>>(Wt, Wp, Wg, Wf, WT_hi, WT_lo, WfT);
    proj_kernel<<<dim3(BN_ / 128, 3), 256, 0, stream>>>(x, WT_hi, WT_lo, ws);
    pool_kernel<<<dim3(N_ / 64, B_), 256, 0, stream>>>(phi_r, g_r, pphi, pgT);
    attn_kernel<<<dim3(N_ / 128, KSPLIT, B_), 256, 0, stream>>>(
        theta, pphi, pgT, ypart, mstat, lstat);
    final_kernel<<<dim3(BN_ / 128, 2), 256, 0, stream>>>(
        ypart, mstat, lstat, x, WfT, out);
}